// Round 8
// baseline (362.776 us; speedup 1.0000x reference)
//
#include <hip/hip_runtime.h>

#define BB 4
#define LL 1024
#define DD 512
#define HH 8
#define NROWS 4096          // BB*LL
#define MiB (1u<<20)

typedef __attribute__((ext_vector_type(8))) short bf16x8;
typedef __attribute__((ext_vector_type(4))) float f32x4;
typedef unsigned short u16;

// fragment-major layouts (elem offsets in u16 units)
__device__ __forceinline__ size_t akf(int tile, int hf, int lane) {
  return (((size_t)tile * 2 + hf) * 64 + lane) * 8;
}
__device__ __forceinline__ size_t vff(int kb, int dt, int lane) {
  return (((size_t)kb * 4 + dt) * 64 + lane) * 8;
}
__device__ __forceinline__ size_t wff(int nt, int kb, int lane) {
  return (((size_t)nt * 16 + kb) * 64 + lane) * 8;
}
#define BH_FRAG 65536   // per-(b,h) frag elems for Q/K/V/CTX

// ---------------- threefry2x32, key = (0, 42) ------------------------------
__device__ __forceinline__ void threefry(unsigned int x0, unsigned int x1,
                                          unsigned int& o0, unsigned int& o1) {
  const unsigned int k0 = 0u, k1 = 42u;
  const unsigned int k2 = k0 ^ k1 ^ 0x1BD11BDAu;
  x0 += k0; x1 += k1;
#define TFR(r) { x0 += x1; x1 = (x1 << (r)) | (x1 >> (32 - (r))); x1 ^= x0; }
  TFR(13) TFR(15) TFR(26) TFR(6)
  x0 += k1; x1 += k2 + 1u;
  TFR(17) TFR(29) TFR(16) TFR(24)
  x0 += k2; x1 += k0 + 2u;
  TFR(13) TFR(15) TFR(26) TFR(6)
  x0 += k0; x1 += k1 + 3u;
  TFR(17) TFR(29) TFR(16) TFR(24)
  x0 += k1; x1 += k2 + 4u;
  TFR(13) TFR(15) TFR(26) TFR(6)
  x0 += k2; x1 += k0 + 5u;
#undef TFR
  o0 = x0; o1 = x1;
}

// hi/lo truncation split
__device__ __forceinline__ void split2(float x, short& h, short& l) {
  unsigned int u = __float_as_uint(x);
  h = (short)(u >> 16);
  float hf = __uint_as_float(u & 0xFFFF0000u);
  l = (short)(__float_as_uint(x - hf) >> 16);
}

__device__ __forceinline__ float bred(float v, float* red, int n, int op) {
  int t = threadIdx.x;
  red[t] = v; __syncthreads();
  for (int s = n >> 1; s > 0; s >>= 1) {
    if (t < s) {
      float a = red[t], b = red[t + s];
      red[t] = (op == 0) ? (a + b) : (op == 1 ? fmaxf(a, b) : fminf(a, b));
    }
    __syncthreads();
  }
  float r = red[0]; __syncthreads();
  return r;
}

// ---------------- LN row stats for q/k/v (mu, rstd) -------------------------
__global__ void k_rowstats(const float* __restrict__ xq, const float* __restrict__ xk,
                           const float* __restrict__ xv, float* __restrict__ st) {
  int bid = blockIdx.x;
  int which = bid >> 12;
  int row = bid & 4095;
  const float* x = (which == 0) ? xq : (which == 1 ? xk : xv);
  float* stp = st + (size_t)which * 2 * NROWS;
  int t = threadIdx.x;             // 64
  float s = 0.f, sq = 0.f;
  for (int i = t; i < DD; i += 64) {
    float v = x[(size_t)row * DD + i];
    s += v; sq += v * v;
  }
  for (int off = 32; off; off >>= 1) { s += __shfl_down(s, off); sq += __shfl_down(sq, off); }
  if (t == 0) {
    float mu = s / 512.f;
    float var = sq / 512.f - mu * mu;
    stp[row * 2] = mu;
    stp[row * 2 + 1] = 1.0f / sqrtf(var + 1e-5f);
  }
}

// ---------------- per-(b,d) partials ---------------------------------------
__global__ void k_bd1(const float* __restrict__ x, float* __restrict__ psum,
                      float* __restrict__ psd2) {
  int c = blockIdx.x, b = blockIdx.y, d = threadIdx.x;
  const float* xb = x + (size_t)b * LL * DD + d;
  int l0 = c * 64;
  float prev = xb[(size_t)l0 * DD];
  float s = prev, sd2 = 0.f;
  for (int i = 1; i < 64; ++i) {
    float v = xb[(size_t)(l0 + i) * DD];
    s += v;
    float dd = v - prev; sd2 += dd * dd; prev = v;
  }
  if (c < 15) {
    float v = xb[(size_t)(l0 + 64) * DD];
    float dd = v - prev; sd2 += dd * dd;
  }
  psum[(b * 16 + c) * DD + d] = s;
  psd2[(b * 16 + c) * DD + d] = sd2;
}

// fused: xmean/vard + per-batch freq (one block per batch, 512 thr)
__global__ __launch_bounds__(512) void k_bd2f(const float* __restrict__ x,
                      const float* __restrict__ psum, const float* __restrict__ psd2,
                      float* __restrict__ xmean, float* __restrict__ frq) {
  __shared__ float red[512];
  int b = blockIdx.x, d = threadIdx.x;
  float s = 0.f, sd2 = 0.f;
  for (int c = 0; c < 16; ++c) { s += psum[(b * 16 + c) * DD + d]; sd2 += psd2[(b * 16 + c) * DD + d]; }
  xmean[b * DD + d] = s * (1.f / 1024.f);
  float S = x[(size_t)b * LL * DD + (size_t)1023 * DD + d] - x[(size_t)b * LL * DD + d];
  float vard = (sd2 - S * S / 1023.f) / 1022.f;
  red[d] = vard; __syncthreads();
  for (int s2 = 256; s2; s2 >>= 1) { if (d < s2) red[d] += red[d + s2]; __syncthreads(); }
  if (d == 0) frq[b] = red[0] / 512.f;
}

// ---------------- per-position stats ---------------------------------------
__global__ void k_perpos(const float* __restrict__ x, const float* __restrict__ xmean,
                         float* __restrict__ comb, float* __restrict__ dmw,
                         float* __restrict__ magw, float* __restrict__ chw,
                         float* __restrict__ fsvw, float* __restrict__ tiww) {
  __shared__ float red[128];
  int bid = blockIdx.x;
  int b = bid >> 10, l = bid & 1023;
  int t = threadIdx.x;               // 128
  const float* xb = x + (size_t)b * LL * DD;
  int s0 = (l - 2 > 0) ? (l - 2) : 0;
  int e0 = (l + 3 < 1024) ? (l + 3) : 1024;
  float n = (float)(e0 - s0);
  float s_comb = 0.f, s_dm = 0.f, s_mag = 0.f, s_ch = 0.f, s_var = 0.f, s_ti = 0.f;
  for (int d = t; d < DD; d += 128) {
    float x0 = xb[(size_t)l * DD + d];
    float d1 = (l + 1 <= 1023) ? fabsf(xb[(size_t)(l + 1) * DD + d] - x0) / 1.0f : 0.f;
    float d2 = (l + 2 <= 1023) ? fabsf(xb[(size_t)(l + 2) * DD + d] - x0) / 2.0f : 0.f;
    float d3 = (l + 3 <= 1023) ? fabsf(xb[(size_t)(l + 3) * DD + d] - x0) / 3.0f : 0.f;
    float d4 = (l + 4 <= 1023) ? fabsf(xb[(size_t)(l + 4) * DD + d] - x0) / 4.0f : 0.f;
    float d5 = (l + 5 <= 1023) ? fabsf(xb[(size_t)(l + 5) * DD + d] - x0) / 5.0f : 0.f;
    s_comb += 0.5f * d1 + 0.3f * d2 + 0.2f * d4;
    s_dm   += 0.4f * d1 + 0.3f * d2 + 0.2f * d3 + 0.1f * d5;
    s_mag  += x0 * x0;
    s_ch   += d1;
    s_ti   += (l <= 1022) ? fabsf(xb[(size_t)(l + 1) * DD + d] - xmean[b * DD + d]) : 0.f;
    float ws = 0.f, wq = 0.f;
    for (int r = s0; r < e0; ++r) { float v = xb[(size_t)r * DD + d]; ws += v; wq += v * v; }
    s_var += (wq - ws * ws / n) / (n - 1.f);
  }
  float r;
  r = bred(s_comb, red, 128, 0); if (t == 0) comb[bid] = r / 512.f;
  r = bred(s_dm,   red, 128, 0); if (t == 0) dmw[bid]  = r / 512.f;
  r = bred(s_mag,  red, 128, 0); if (t == 0) magw[bid] = sqrtf(r);
  r = bred(s_ch,   red, 128, 0); if (t == 0) chw[bid]  = r / 512.f;
  r = bred(s_var,  red, 128, 0); if (t == 0) fsvw[bid] = r / 512.f;
  r = bred(s_ti,   red, 128, 0); if (t == 0) tiww[bid] = r / 512.f;
}

// ---------------- per-batch: windows, keypoints + fused gumbel top-k --------
__global__ __launch_bounds__(1024) void k_batch(
    const float* __restrict__ comb, const float* __restrict__ dmw,
    const float* __restrict__ magw, const float* __restrict__ chw,
    const float* __restrict__ fsvw, const float* __restrict__ tiww,
    const float* __restrict__ frq,
    int* __restrict__ winlo, int* __restrict__ winhi,
    unsigned char* __restrict__ rowall, unsigned char* __restrict__ colf) {
  __shared__ float red[1024];
  __shared__ float sdm[1024];
  __shared__ int si[1024];
  __shared__ int anykp;
  int b = blockIdx.x, l = threadIdx.x;
  int idx = b * 1024 + l;
  float vcomb = comb[idx], vdm = dmw[idx], vmag = magw[idx];
  float vch = chw[idx], vfsv = fsvw[idx], vti = tiww[idx];
  float fqb = frq[b];
  sdm[l] = vdm;
  if (l == 0) anykp = 0;

  float cmin = bred(vcomb, red, 1024, 2);
  float cmax = bred(vcomb, red, 1024, 1);
  float impw = (vcomb - cmin) / (cmax - cmin + 1e-6f);
  int localw = (int)rintf(32.f * (0.5f + 0.5f * impw));
  localw = localw < 2 ? 2 : (localw > 64 ? 64 : localw);

  float tmin = bred(vti, red, 1024, 2);
  float tmax = bred(vti, red, 1024, 1);
  float tin = (vti - tmin) / (tmax - tmin + 1e-6f);
  int futw = (int)rintf(16.f * (0.5f + 0.5f * tin));
  futw = futw < 1 ? 1 : (futw > 16 ? 16 : futw);

  float dmean = bred(vdm, red, 1024, 0) / 1024.f;
  float dd = vdm - dmean;
  float dvar = bred(dd * dd, red, 1024, 0) / 1023.f;
  float thr = dmean + 0.5f * sqrtf(dvar);

  bool kp;
  if (l == 0 || l == 1023) kp = vdm > thr;
  else kp = (vdm > sdm[l - 1]) && (vdm > sdm[l + 1]) && (vdm > thr);
  if (kp) atomicOr(&anykp, 1);

  float fs = (l == 0 || l == 1023) ? 0.f : vfsv / (fqb + 1e-6f);
  float ig = vmag * 0.3f + vch * 0.4f + fs * 0.3f;
  float gmin = bred(ig, red, 1024, 2);
  float gmax = bred(ig, red, 1024, 1);   // bred syncs => anykp published
  float impn = (ig - gmin) / (gmax - gmin + 1e-6f);

  int any = anykp;
  winlo[idx] = l - localw;
  winhi[idx] = l + (localw > futw ? localw : futw);
  rowall[idx] = (any && kp) ? 1 : 0;
  bool fbcol = (l == 0 || l == 255 || l == 511 || l == 767 || l == 1023);
  colf[idx] = any ? (kp ? 1 : 0) : (fbcol ? 1 : 0);

  // ---- fused gumbel top-4 per 256-segment (layer = l>>8, j = l&255) -------
  int j = l & 255, seg0 = l & ~255;
  red[l] = impn; __syncthreads();
  for (int s = 128; s; s >>= 1) { if (j < s) red[l] += red[l + s]; __syncthreads(); }
  float ssum = red[seg0]; __syncthreads();
  float logit = logf(impn / ssum + 1e-20f);
  unsigned int o0, o1;
  threefry(0u, (unsigned int)idx, o0, o1);
  unsigned int bits = o0 ^ o1;
  float u = __uint_as_float((bits >> 9) | 0x3f800000u) - 1.0f;
  float g = -logf(-logf(u + 1e-20f) + 1e-20f);
  float key = logit + g;
  for (int pick = 0; pick < 4; ++pick) {
    red[l] = key; si[l] = j; __syncthreads();
    for (int s = 128; s; s >>= 1) {
      if (j < s) { if (red[l + s] > red[l]) { red[l] = red[l + s]; si[l] = si[l + s]; } }
      __syncthreads();
    }
    int w = si[seg0]; __syncthreads();
    if (j == w) { key = -1e30f; colf[idx] = 1; }
  }
}

// ---------------- split 5 weight matrices to frag-major hi/lo bf16 ----------
struct WArgs { const float* s[5]; u16* h[5]; u16* l[5]; };
__global__ void k_split_w(WArgs a) {
  int slot = blockIdx.x * 512 + threadIdx.x;   // 0..32767
  int lane = slot & 63;
  int kb = (slot >> 6) & 15, nt = slot >> 10;
  int c16 = lane & 15, g4 = lane >> 4;
  int n = nt * 16 + c16, k = kb * 32 + g4 * 8;
#pragma unroll
  for (int m = 0; m < 5; ++m) {
    const float* src = a.s[m] + (size_t)n * DD + k;
    float4 v0 = *(const float4*)src;
    float4 v1 = *(const float4*)(src + 4);
    float v[8] = {v0.x, v0.y, v0.z, v0.w, v1.x, v1.y, v1.z, v1.w};
    bf16x8 hv, lv;
#pragma unroll
    for (int j = 0; j < 8; ++j) {
      short hh, ll; split2(v[j], hh, ll);
      hv[j] = hh; lv[j] = ll;
    }
    *(bf16x8*)&a.h[m][(size_t)slot * 8] = hv;
    *(bf16x8*)&a.l[m][(size_t)slot * 8] = lv;
  }
}

// ---------------- QKV projection: MFMA split-bf16, frag-major outputs -------
struct QkvArgs {
  const float* X[3]; const float* stats[3]; const float* lnw[3]; const float* lnb[3];
  const float* bias[3]; const u16* Wh[3]; const u16* Wl[3];
  u16* oh[3]; u16* ol[3];
};
__global__ __launch_bounds__(256, 2) void k_gemm_qkv(QkvArgs a) {
  __shared__ float scr[4][1088];
  int z = blockIdx.z;
  int t = threadIdx.x, w = t >> 6, lane = t & 63, c16 = lane & 15, g4 = lane >> 4;
  int mbase = blockIdx.x * 256 + w * 64;
  int head = blockIdx.y, n0 = head * 64;
  const float* X = a.X[z];
  const float* stp = a.stats[z];
  const float* lnw = a.lnw[z];
  const float* lnb = a.lnb[z];
  const u16* Wh = a.Wh[z];
  const u16* Wl = a.Wl[z];
  const float* bias = a.bias[z];
  float scale = (z == 0) ? 0.125f : 1.0f;

  int rows[4]; float mu[4], rsd[4];
#pragma unroll
  for (int mi = 0; mi < 4; ++mi) {
    rows[mi] = mbase + mi * 16 + c16;
    mu[mi] = stp[rows[mi] * 2];
    rsd[mi] = stp[rows[mi] * 2 + 1];
  }
  f32x4 acc[4][4];
#pragma unroll
  for (int mi = 0; mi < 4; ++mi)
#pragma unroll
    for (int ni = 0; ni < 4; ++ni) acc[mi][ni] = (f32x4){0.f, 0.f, 0.f, 0.f};

  for (int k0 = 0; k0 < 512; k0 += 32) {
    int kk = k0 + g4 * 8;
    float4 w0 = *(const float4*)&lnw[kk];
    float4 w1 = *(const float4*)&lnw[kk + 4];
    float4 lb0 = *(const float4*)&lnb[kk];
    float4 lb1 = *(const float4*)&lnb[kk + 4];
    float lw[8] = {w0.x, w0.y, w0.z, w0.w, w1.x, w1.y, w1.z, w1.w};
    float lb[8] = {lb0.x, lb0.y, lb0.z, lb0.w, lb1.x, lb1.y, lb1.z, lb1.w};
    bf16x8 ah[4], al[4];
#pragma unroll
    for (int mi = 0; mi < 4; ++mi) {
      const float* xp = &X[(size_t)rows[mi] * DD + kk];
      float4 xa = *(const float4*)xp;
      float4 xb = *(const float4*)(xp + 4);
      float v[8] = {xa.x, xa.y, xa.z, xa.w, xb.x, xb.y, xb.z, xb.w};
#pragma unroll
      for (int j = 0; j < 8; ++j) {
        float y = fmaf((v[j] - mu[mi]) * rsd[mi], lw[j], lb[j]);
        short hh, ll; split2(y, hh, ll);
        ah[mi][j] = hh; al[mi][j] = ll;
      }
    }
    bf16x8 bh[4], bl[4];
    int kb32 = k0 >> 5;
#pragma unroll
    for (int ni = 0; ni < 4; ++ni) {
      size_t wo = wff(head * 4 + ni, kb32, lane);
      bh[ni] = *(const bf16x8*)&Wh[wo];
      bl[ni] = *(const bf16x8*)&Wl[wo];
    }
#pragma unroll
    for (int mi = 0; mi < 4; ++mi)
#pragma unroll
      for (int ni = 0; ni < 4; ++ni) {
        acc[mi][ni] = __builtin_amdgcn_mfma_f32_16x16x32_bf16(ah[mi], bh[ni], acc[mi][ni], 0, 0, 0);
        acc[mi][ni] = __builtin_amdgcn_mfma_f32_16x16x32_bf16(ah[mi], bl[ni], acc[mi][ni], 0, 0, 0);
        acc[mi][ni] = __builtin_amdgcn_mfma_f32_16x16x32_bf16(al[mi], bh[ni], acc[mi][ni], 0, 0, 0);
      }
  }

  int b = mbase >> 10, lr0 = mbase & 1023;
  size_t bhbase = (size_t)(b * HH + head) * BH_FRAG;
  if (z < 2) {
    u16* oh = a.oh[z]; u16* ol = a.ol[z];
    int row16 = lane >> 2, dseg = (lane & 3) * 16;
    float bs[16];
#pragma unroll
    for (int j = 0; j < 16; j += 4) {
      float4 bb = *(const float4*)&bias[n0 + dseg + j];
      bs[j] = bb.x; bs[j + 1] = bb.y; bs[j + 2] = bb.z; bs[j + 3] = bb.w;
    }
    int hf = dseg >> 5, g4a = (dseg >> 3) & 3;
#pragma unroll
    for (int mi = 0; mi < 4; ++mi) {
#pragma unroll
      for (int ni = 0; ni < 4; ++ni)
#pragma unroll
        for (int r = 0; r < 4; ++r)
          scr[w][(g4 * 4 + r) * 68 + ni * 16 + c16] = acc[mi][ni][r];
      float f[16];
#pragma unroll
      for (int j = 0; j < 16; j += 4) {
        float4 q = *(const float4*)&scr[w][row16 * 68 + dseg + j];
        f[j] = q.x; f[j + 1] = q.y; f[j + 2] = q.z; f[j + 3] = q.w;
      }
      bf16x8 fh[2], fl[2];
#pragma unroll
      for (int j = 0; j < 16; ++j) {
        short hh, ll; split2((f[j] + bs[j]) * scale, hh, ll);
        fh[j >> 3][j & 7] = hh; fl[j >> 3][j & 7] = ll;
      }
      int tile = (lr0 + mi * 16) >> 4;
      size_t ad1 = bhbase + akf(tile, hf, g4a * 16 + row16);
      size_t ad2 = bhbase + akf(tile, hf, (g4a + 1) * 16 + row16);
      *(bf16x8*)&oh[ad1] = fh[0]; *(bf16x8*)&oh[ad2] = fh[1];
      *(bf16x8*)&ol[ad1] = fl[0]; *(bf16x8*)&ol[ad2] = fl[1];
    }
  } else {
    u16* oh = a.oh[2]; u16* ol = a.ol[2];
#pragma unroll
    for (int ni = 0; ni < 4; ++ni) {
#pragma unroll
      for (int mi = 0; mi < 4; ++mi)
#pragma unroll
        for (int r = 0; r < 4; ++r)
          scr[w][(mi * 16 + g4 * 4 + r) * 17 + c16] = acc[mi][ni][r];
      float bb = bias[n0 + ni * 16 + c16];
#pragma unroll
      for (int kbloc = 0; kbloc < 2; ++kbloc) {
        bf16x8 hv, lv;
#pragma unroll
        for (int j = 0; j < 8; ++j) {
          float y = scr[w][(kbloc * 32 + g4 * 8 + j) * 17 + c16] + bb;
          short hh, ll; split2(y, hh, ll);
          hv[j] = hh; lv[j] = ll;
        }
        int kb = (lr0 >> 5) + kbloc;
        size_t ad = bhbase + vff(kb, ni, lane);
        *(bf16x8*)&oh[ad] = hv;
        *(bf16x8*)&ol[ad] = lv;
      }
    }
  }
}

// ---------------- flash attention: 4-way kv split, 4-way combine ------------
// grid (64, HH, BB) x 256 thr (4 waves). Block = one 16-row q-tile.
// Wave w handles kv quarter [w*256, (w+1)*256) as 4 chunks of 64 (skippable).
// End: 4-way flash combine in LDS, wave 0 stores CTX frag-major into Q bufs.
__global__ __launch_bounds__(256, 4) void k_attn_mfma(
    const u16* Qh, const u16* Ql, const u16* Kh, const u16* Kl,
    const u16* Vh, const u16* Vl,
    const int* __restrict__ winlo, const int* __restrict__ winhi,
    const unsigned char* __restrict__ rowall, const unsigned char* __restrict__ colf,
    u16* Ch, u16* Cl) {
  __shared__ float Pl_s[4][16][68];
  __shared__ unsigned char scolf[1024];
  __shared__ int schunk[16];
  int qt = blockIdx.x, h = blockIdx.y, b = blockIdx.z;
  int t = threadIdx.x, w = t >> 6, lane = t & 63;
  int c16 = lane & 15, g4 = lane >> 4;
  int q0 = qt * 16;
  int qtile = qt;
  size_t bhbase = (size_t)(b * HH + h) * BH_FRAG;

  for (int i = t; i < 1024; i += 256) scolf[i] = colf[b * 1024 + i];
  __syncthreads();
  if (t < 16) {
    int any = 0;
    const int* p32 = (const int*)&scolf[t * 64];
#pragma unroll
    for (int j = 0; j < 16; ++j) any |= p32[j];
    schunk[t] = any;
  }

  const u16* Qfh = Qh + bhbase;
  const u16* Qfl = Ql + bhbase;
  bf16x8 qh0 = *(const bf16x8*)&Qfh[akf(qtile, 0, lane)];
  bf16x8 qh1 = *(const bf16x8*)&Qfh[akf(qtile, 1, lane)];
  bf16x8 ql0 = *(const bf16x8*)&Qfl[akf(qtile, 0, lane)];
  bf16x8 ql1 = *(const bf16x8*)&Qfl[akf(qtile, 1, lane)];

  int elo[4], ehi[4];
#pragma unroll
  for (int r = 0; r < 4; ++r) {
    int row = b * 1024 + q0 + g4 * 4 + r;
    int ra = rowall[row];
    elo[r] = ra ? 0 : winlo[row];
    ehi[r] = ra ? 1023 : winhi[row];
  }
  int tlo = min(min(elo[0], elo[1]), min(elo[2], elo[3]));
  int thi = max(max(ehi[0], ehi[1]), max(ehi[2], ehi[3]));
  tlo = min(tlo, __shfl_xor(tlo, 16)); tlo = min(tlo, __shfl_xor(tlo, 32));
  thi = max(thi, __shfl_xor(thi, 16)); thi = max(thi, __shfl_xor(thi, 32));
  __syncthreads();   // scolf + schunk ready

  const u16* Kfh = Kh + bhbase;
  const u16* Kfl = Kl + bhbase;
  const u16* Vfh = Vh + bhbase;
  const u16* Vfl = Vl + bhbase;

  float m[4] = {-1e30f, -1e30f, -1e30f, -1e30f};
  float lsum[4] = {0.f, 0.f, 0.f, 0.f};
  f32x4 accO[4];
#pragma unroll
  for (int dt = 0; dt < 4; ++dt) accO[dt] = (f32x4){0.f, 0.f, 0.f, 0.f};

  int kvbase = w * 256;
  for (int kt = 0; kt < 4; ++kt) {
    int kb0 = kvbase + kt * 64;
    if (!schunk[kb0 >> 6] && (kb0 > thi || kb0 + 63 < tlo)) continue;
    // ---- K fragments (coalesced) -------------------------------------------
    bf16x8 kf[4][4];
#pragma unroll
    for (int tt = 0; tt < 4; ++tt) {
      int kt16 = (kb0 >> 4) + tt;
      kf[tt][0] = *(const bf16x8*)&Kfh[akf(kt16, 0, lane)];
      kf[tt][1] = *(const bf16x8*)&Kfh[akf(kt16, 1, lane)];
      kf[tt][2] = *(const bf16x8*)&Kfl[akf(kt16, 0, lane)];
      kf[tt][3] = *(const bf16x8*)&Kfl[akf(kt16, 1, lane)];
    }
    f32x4 s[4];
#pragma unroll
    for (int tt = 0; tt < 4; ++tt) {
      f32x4 a = (f32x4){0.f, 0.f, 0.f, 0.f};
      a = __builtin_amdgcn_mfma_f32_16x16x32_bf16(qh0, kf[tt][0], a, 0, 0, 0);
      a = __builtin_amdgcn_mfma_f32_16x16x32_bf16(qh1, kf[tt][1], a, 0, 0, 0);
      a = __builtin_amdgcn_mfma_f32_16x16x32_bf16(qh0, kf[tt][2], a, 0, 0, 0);
      a = __builtin_amdgcn_mfma_f32_16x16x32_bf16(qh1, kf[tt][3], a, 0, 0, 0);
      a = __builtin_amdgcn_mfma_f32_16x16x32_bf16(ql0, kf[tt][0], a, 0, 0, 0);
      a = __builtin_amdgcn_mfma_f32_16x16x32_bf16(ql1, kf[tt][1], a, 0, 0, 0);
      s[tt] = a;
    }
    // ---- V batch load (overlaps softmax) -----------------------------------
    bf16x8 vf[2][4][2];
#pragma unroll
    for (int ks = 0; ks < 2; ++ks) {
      int kb = (kb0 >> 5) + ks;
#pragma unroll
      for (int dt = 0; dt < 4; ++dt) {
        vf[ks][dt][0] = *(const bf16x8*)&Vfh[vff(kb, dt, lane)];
        vf[ks][dt][1] = *(const bf16x8*)&Vfl[vff(kb, dt, lane)];
      }
    }
    // ---- mask + online softmax ---------------------------------------------
    float mr[4] = {-1e30f, -1e30f, -1e30f, -1e30f};
#pragma unroll
    for (int tt = 0; tt < 4; ++tt) {
      int kv = kb0 + tt * 16 + c16;
      bool cf = scolf[kv] != 0;
#pragma unroll
      for (int r = 0; r < 4; ++r) {
        bool vis = cf || (kv >= elo[r] && kv <= ehi[r]);
        float v = vis ? s[tt][r] : -1e9f;
        s[tt][r] = v;
        mr[r] = fmaxf(mr[r], v);
      }
    }
#pragma unroll
    for (int off = 1; off < 16; off <<= 1)
#pragma unroll
      for (int r = 0; r < 4; ++r) mr[r] = fmaxf(mr[r], __shfl_xor(mr[r], off));
    float sc[4], rs[4];
#pragma unroll
    for (int r = 0; r < 4; ++r) {
      float mn = fmaxf(m[r], mr[r]);
      sc[r] = __expf(m[r] - mn);
      m[r] = mn;
      rs[r] = 0.f;
    }
#pragma unroll
    for (int tt = 0; tt < 4; ++tt)
#pragma unroll
      for (int r = 0; r < 4; ++r) {
        float p = __expf(s[tt][r] - m[r]);
        s[tt][r] = p;
        rs[r] += p;
      }
#pragma unroll
    for (int off = 1; off < 16; off <<= 1)
#pragma unroll
      for (int r = 0; r < 4; ++r) rs[r] += __shfl_xor(rs[r], off);
#pragma unroll
    for (int r = 0; r < 4; ++r) lsum[r] = lsum[r] * sc[r] + rs[r];
#pragma unroll
    for (int dt = 0; dt < 4; ++dt)
#pragma unroll
      for (int r = 0; r < 4; ++r) accO[dt][r] *= sc[r];
    // ---- P -> per-wave LDS transpose, then PV ------------------------------
#pragma unroll
    for (int tt = 0; tt < 4; ++tt)
#pragma unroll
      for (int r = 0; r < 4; ++r)
        Pl_s[w][g4 * 4 + r][tt * 16 + c16] = s[tt][r];
#pragma unroll
    for (int ks = 0; ks < 2; ++ks) {
      const float* prow = &Pl_s[w][c16][ks * 32 + g4 * 8];
      float4 pa = *(const float4*)(prow);
      float4 pb = *(const float4*)(prow + 4);
      float pv[8] = {pa.x, pa.y, pa.z, pa.w, pb.x, pb.y, pb.z, pb.w};
      bf16x8 pah, pal;
#pragma unroll
      for (int j = 0; j < 8; ++j) {
        short hh, ll; split2(pv[j], hh, ll);
        pah[j] = hh; pal[j] = ll;
      }
#pragma unroll
      for (int dt = 0; dt < 4; ++dt) {
        accO[dt] = __builtin_amdgcn_mfma_f32_16x16x32_bf16(pah, vf[ks][dt][0], accO[dt], 0, 0, 0);
        accO[dt] = __builtin_amdgcn_mfma_f32_16x16x32_bf16(pah, vf[ks][dt][1], accO[dt], 0, 0, 0);
        accO[dt] = __builtin_amdgcn_mfma_f32_16x16x32_bf16(pal, vf[ks][dt][0], accO[dt], 0, 0, 0);
      }
    }
  }
  // ---- 4-way combine: waves 1..3 publish partials, wave 0 merges -----------
  if (w > 0) {
#pragma unroll
    for (int dt = 0; dt < 4; ++dt)
#pragma unroll
      for (int r = 0; r < 4; ++r)
        Pl_s[w][g4 * 4 + r][dt * 16 + c16] = accO[dt][r];
    if (c16 == 0) {
#pragma unroll
      for (int r = 0; r < 4; ++r) {
        Pl_s[w][g4 * 4 + r][64] = m[r];
        Pl_s[w][g4 * 4 + r][65] = lsum[r];
      }
    }
  }
  __syncthreads();
  if (w == 0) {
    float M[4], L[4];
#pragma unroll
    for (int r = 0; r < 4; ++r) { M[r] = m[r]; }
#pragma unroll
    for (int i = 1; i < 4; ++i)
#pragma unroll
      for (int r = 0; r < 4; ++r)
        M[r] = fmaxf(M[r], Pl_s[i][g4 * 4 + r][64]);
    float w0[4];
#pragma unroll
    for (int r = 0; r < 4; ++r) {
      w0[r] = __expf(m[r] - M[r]);
      L[r] = lsum[r] * w0[r];
    }
    float y[4][4];
#pragma unroll
    for (int dt = 0; dt < 4; ++dt)
#pragma unroll
      for (int r = 0; r < 4; ++r) y[dt][r] = accO[dt][r] * w0[r];
#pragma unroll
    for (int i = 1; i < 4; ++i) {
      float wi[4];
#pragma unroll
      for (int r = 0; r < 4; ++r) {
        float mi = Pl_s[i][g4 * 4 + r][64];
        float li = Pl_s[i][g4 * 4 + r][65];
        wi[r] = __expf(mi - M[r]);
        L[r] += li * wi[r];
      }
#pragma unroll
      for (int dt = 0; dt < 4; ++dt)
#pragma unroll
        for (int r = 0; r < 4; ++r)
          y[dt][r] += Pl_s[i][g4 * 4 + r][dt * 16 + c16] * wi[r];
    }
    float inv[4];
#pragma unroll
    for (int r = 0; r < 4; ++r) inv[r] = 1.0f / L[r];
#pragma unroll
    for (int dt = 0; dt < 4; ++dt)
#pragma unroll
      for (int r = 0; r < 4; ++r)
        Pl_s[0][g4 * 4 + r][dt * 16 + c16] = y[dt][r] * inv[r];
    // wave-local transpose -> AK-frag store
    int row16 = lane >> 2, dseg = (lane & 3) * 16;
    int hf = dseg >> 5, g4a = (dseg >> 3) & 3;
    float f[16];
#pragma unroll
    for (int j = 0; j < 16; j += 4) {
      float4 q = *(const float4*)&Pl_s[0][row16][dseg + j];
      f[j] = q.x; f[j + 1] = q.y; f[j + 2] = q.z; f[j + 3] = q.w;
    }
    bf16x8 fh[2], fl[2];
#pragma unroll
    for (int j = 0; j < 16; ++j) {
      short hh, ll; split2(f[j], hh, ll);
      fh[j >> 3][j & 7] = hh; fl[j >> 3][j & 7] = ll;
    }
    size_t ad1 = bhbase + akf(qtile, hf, g4a * 16 + row16);
    size_t ad2 = bhbase + akf(qtile, hf, (g4a + 1) * 16 + row16);
    *(bf16x8*)&Ch[ad1] = fh[0]; *(bf16x8*)&Ch[ad2] = fh[1];
    *(bf16x8*)&Cl[ad1] = fl[0]; *(bf16x8*)&Cl[ad2] = fl[1];
  }
}

// ---------------- final dual GEMM (MFMA) ------------------------------------
struct OutArgs {
  const u16* Ch; const u16* Cl; const float* XQ;
  const u16* Woh; const u16* Wol; const u16* Wgh; const u16* Wgl;
  const float* bo; const float* bg; float* out;
};
__global__ __launch_bounds__(256, 2) void k_gemm_out(OutArgs a) {
  int t = threadIdx.x, w = t >> 6, lane = t & 63, c16 = lane & 15, g4 = lane >> 4;
  int mbase = blockIdx.x * 256 + w * 64;
  int n0 = blockIdx.y * 32;
  int rows[4];
#pragma unroll
  for (int mi = 0; mi < 4; ++mi) rows[mi] = mbase + mi * 16 + c16;
  int bidx = mbase >> 10, lr0 = mbase & 1023;
  f32x4 accO[4][2], accG[4][2];
#pragma unroll
  for (int mi = 0; mi < 4; ++mi)
#pragma unroll
    for (int ni = 0; ni < 2; ++ni) {
      accO[mi][ni] = (f32x4){0.f, 0.f, 0.f, 0.f};
      accG[mi][ni] = (f32x4){0.f, 0.f, 0.f, 0.f};
    }
  for (int k0 = 0; k0 < 512; k0 += 32) {
    int kk = k0 + g4 * 8;
    int hsel = kk >> 6, hf = (kk >> 5) & 1;
    int kb32 = k0 >> 5;
    bf16x8 ch[4], cl[4], gh[4], gl[4];
#pragma unroll
    for (int mi = 0; mi < 4; ++mi) {
      int ctile = (lr0 + mi * 16) >> 4;
      size_t cb = (size_t)(bidx * HH + hsel) * BH_FRAG + akf(ctile, hf, lane);
      ch[mi] = *(const bf16x8*)&a.Ch[cb];
      cl[mi] = *(const bf16x8*)&a.Cl[cb];
      const float* xp = &a.XQ[(size_t)rows[mi] * DD + kk];
      float4 xa = *(const float4*)xp;
      float4 xb = *(const float4*)(xp + 4);
      float v[8] = {xa.x, xa.y, xa.z, xa.w, xb.x, xb.y, xb.z, xb.w};
#pragma unroll
      for (int j = 0; j < 8; ++j) {
        short hh, ll; split2(v[j], hh, ll);
        gh[mi][j] = hh; gl[mi][j] = ll;
      }
    }
    bf16x8 woh[2], wol[2], wgh[2], wgl[2];
#pragma unroll
    for (int ni = 0; ni < 2; ++ni) {
      size_t wo = wff((n0 >> 4) + ni, kb32, lane);
      woh[ni] = *(const bf16x8*)&a.Woh[wo];
      wol[ni] = *(const bf16x8*)&a.Wol[wo];
      wgh[ni] = *(const bf16x8*)&a.Wgh[wo];
      wgl[ni] = *(const bf16x8*)&a.Wgl[wo];
    }
#pragma unroll
    for (int mi = 0; mi < 4; ++mi)
#pragma unroll
      for (int ni = 0; ni < 2; ++ni) {
        accO[mi][ni] = __builtin_amdgcn_mfma_f32_16x16x32_bf16(ch[mi], woh[ni], accO[mi][ni], 0, 0, 0);
        accO[mi][ni] = __builtin_amdgcn_mfma_f32_16x16x32_bf16(ch[mi], wol[ni], accO[mi][ni], 0, 0, 0);
        accO[mi][ni] = __builtin_amdgcn_mfma_f32_16x16x32_bf16(cl[mi], woh[ni], accO[mi][ni], 0, 0, 0);
        accG[mi][ni] = __builtin_amdgcn_mfma_f32_16x16x32_bf16(gh[mi], wgh[ni], accG[mi][ni], 0, 0, 0);
        accG[mi][ni] = __builtin_amdgcn_mfma_f32_16x16x32_bf16(gh[mi], wgl[ni], accG[mi][ni], 0, 0, 0);
        accG[mi][ni] = __builtin_amdgcn_mfma_f32_16x16x32_bf16(gl[mi], wgh[ni], accG[mi][ni], 0, 0, 0);
      }
  }
#pragma unroll
  for (int mi = 0; mi < 4; ++mi)
#pragma unroll
    for (int ni = 0; ni < 2; ++ni) {
      int n = n0 + ni * 16 + c16;
      float bo = a.bo[n], bg = a.bg[n];
#pragma unroll
      for (int r = 0; r < 4; ++r) {
        int l = mbase + mi * 16 + g4 * 4 + r;
        float ov = accO[mi][ni][r] + bo;
        float gp = accG[mi][ni][r] + bg;
        float gate = 1.0f / (1.0f + __expf(-gp));
        a.out[(size_t)l * DD + n] = gate * ov;
      }
    }
}

// ---------------- host launch ----------------------------------------------
extern "C" void kernel_launch(void* const* d_in, const int* in_sizes, int n_in,
                              void* d_out, int out_size, void* d_ws, size_t ws_size,
                              hipStream_t stream) {
  (void)in_sizes; (void)n_in; (void)out_size; (void)ws_size;
  const float* xq = (const float*)d_in[0];
  const float* xk = (const float*)d_in[1];
  const float* xv = (const float*)d_in[2];
  const float* Wq = (const float*)d_in[3];
  const float* bq = (const float*)d_in[4];
  const float* Wk = (const float*)d_in[5];
  const float* bk = (const float*)d_in[6];
  const float* Wv = (const float*)d_in[7];
  const float* bv = (const float*)d_in[8];
  const float* Wo = (const float*)d_in[9];
  const float* bo = (const float*)d_in[10];
  const float* Wg = (const float*)d_in[11];
  const float* bg = (const float*)d_in[12];
  const float* lqw = (const float*)d_in[13];
  const float* lqb = (const float*)d_in[14];
  const float* lkw = (const float*)d_in[15];
  const float* lkb = (const float*)d_in[16];
  const float* lvw = (const float*)d_in[17];
  const float* lvb = (const float*)d_in[18];
  float* out = (float*)d_out;

  char* base = (char*)d_ws;
  u16* Qh = (u16*)(base + (size_t)0 * MiB);
  u16* Ql = (u16*)(base + (size_t)4 * MiB);
  u16* Kh = (u16*)(base + (size_t)8 * MiB);
  u16* Kl = (u16*)(base + (size_t)12 * MiB);
  u16* Vh = (u16*)(base + (size_t)16 * MiB);
  u16* Vl = (u16*)(base + (size_t)20 * MiB);
  u16* Wsp = (u16*)(base + (size_t)24 * MiB);
  u16 *Wqh = Wsp, *Wql = Wsp + 262144, *Wkh = Wsp + 2 * 262144, *Wkl = Wsp + 3 * 262144;
  u16 *Wvh = Wsp + 4 * 262144, *Wvl = Wsp + 5 * 262144;
  u16 *Woh = Wsp + 6 * 262144, *Wol = Wsp + 7 * 262144;
  u16 *Wgh = Wsp + 8 * 262144, *Wgl = Wsp + 9 * 262144;
  float* st = (float*)(base + (size_t)29 * MiB);          // 24576 f
  float* tr = (float*)(base + (size_t)29 * MiB + 131072);
  float* xmean = tr;               // 2048
  float* frq = xmean + 2048;       // 64
  float* comb = frq + 64;
  float* dmw = comb + 4096;
  float* magw = dmw + 4096;
  float* chw = magw + 4096;
  float* fsvw = chw + 4096;
  float* tiww = fsvw + 4096;
  float* psum = tiww + 4096;       // 32768
  float* psd2 = psum + 32768;      // 32768
  int* winlo = (int*)(base + (size_t)30 * MiB);
  int* winhi = winlo + NROWS;
  unsigned char* rowallp = (unsigned char*)(winhi + NROWS);
  unsigned char* colfp = rowallp + NROWS;

  // mask pipeline
  k_rowstats<<<3 * NROWS, 64, 0, stream>>>(xq, xk, xv, st);
  k_bd1<<<dim3(16, BB), 512, 0, stream>>>(xq, psum, psd2);
  k_bd2f<<<BB, 512, 0, stream>>>(xq, psum, psd2, xmean, frq);
  k_perpos<<<NROWS, 128, 0, stream>>>(xq, xmean, comb, dmw, magw, chw, fsvw, tiww);
  k_batch<<<BB, 1024, 0, stream>>>(comb, dmw, magw, chw, fsvw, tiww, frq,
                                   winlo, winhi, rowallp, colfp);

  // weight splits (fragment-major)
  WArgs wa;
  wa.s[0] = Wq; wa.s[1] = Wk; wa.s[2] = Wv; wa.s[3] = Wo; wa.s[4] = Wg;
  wa.h[0] = Wqh; wa.h[1] = Wkh; wa.h[2] = Wvh; wa.h[3] = Woh; wa.h[4] = Wgh;
  wa.l[0] = Wql; wa.l[1] = Wkl; wa.l[2] = Wvl; wa.l[3] = Wol; wa.l[4] = Wgl;
  k_split_w<<<64, 512, 0, stream>>>(wa);

  // QKV projections
  QkvArgs qa;
  qa.X[0] = xq; qa.X[1] = xk; qa.X[2] = xv;
  qa.stats[0] = st; qa.stats[1] = st + 2 * NROWS; qa.stats[2] = st + 4 * NROWS;
  qa.lnw[0] = lqw; qa.lnw[1] = lkw; qa.lnw[2] = lvw;
  qa.lnb[0] = lqb; qa.lnb[1] = lkb; qa.lnb[2] = lvb;
  qa.bias[0] = bq; qa.bias[1] = bk; qa.bias[2] = bv;
  qa.Wh[0] = Wqh; qa.Wh[1] = Wkh; qa.Wh[2] = Wvh;
  qa.Wl[0] = Wql; qa.Wl[1] = Wkl; qa.Wl[2] = Wvl;
  qa.oh[0] = Qh; qa.oh[1] = Kh; qa.oh[2] = Vh;
  qa.ol[0] = Ql; qa.ol[1] = Kl; qa.ol[2] = Vl;
  k_gemm_qkv<<<dim3(16, 8, 3), 256, 0, stream>>>(qa);

  // attention (natural grid order; 4-way kv split; CTX into Q buffers)
  k_attn_mfma<<<dim3(64, HH, BB), 256, 0, stream>>>(Qh, Ql, Kh, Kl, Vh, Vl,
                                                    winlo, winhi, rowallp, colfp,
                                                    Qh, Ql);

  // output dual GEMM
  OutArgs oa;
  oa.Ch = Qh; oa.Cl = Ql; oa.XQ = xq;
  oa.Woh = Woh; oa.Wol = Wol; oa.Wgh = Wgh; oa.Wgl = Wgl;
  oa.bo = bo; oa.bg = bg; oa.out = out;
  k_gemm_out<<<dim3(16, 16), 256, 0, stream>>>(oa);
}

// Round 9
// 215.228 us; speedup vs baseline: 1.6855x; 1.6855x over previous
//
#include <hip/hip_runtime.h>

#define BB 4
#define LL 1024
#define DD 512
#define HH 8
#define NROWS 4096          // BB*LL
#define MiB (1u<<20)

typedef __attribute__((ext_vector_type(8))) short bf16x8;
typedef __attribute__((ext_vector_type(4))) float f32x4;
typedef unsigned short u16;

// fragment-major layouts (elem offsets in u16 units)
__device__ __forceinline__ size_t akf(int tile, int hf, int lane) {
  return (((size_t)tile * 2 + hf) * 64 + lane) * 8;
}
__device__ __forceinline__ size_t vff(int kb, int dt, int lane) {
  return (((size_t)kb * 4 + dt) * 64 + lane) * 8;
}
__device__ __forceinline__ size_t wff(int nt, int kb, int lane) {
  return (((size_t)nt * 16 + kb) * 64 + lane) * 8;
}
#define BH_FRAG 65536   // per-(b,h) frag elems for Q/K/V/CTX

// ---------------- threefry2x32, key = (0, 42) ------------------------------
__device__ __forceinline__ void threefry(unsigned int x0, unsigned int x1,
                                          unsigned int& o0, unsigned int& o1) {
  const unsigned int k0 = 0u, k1 = 42u;
  const unsigned int k2 = k0 ^ k1 ^ 0x1BD11BDAu;
  x0 += k0; x1 += k1;
#define TFR(r) { x0 += x1; x1 = (x1 << (r)) | (x1 >> (32 - (r))); x1 ^= x0; }
  TFR(13) TFR(15) TFR(26) TFR(6)
  x0 += k1; x1 += k2 + 1u;
  TFR(17) TFR(29) TFR(16) TFR(24)
  x0 += k2; x1 += k0 + 2u;
  TFR(13) TFR(15) TFR(26) TFR(6)
  x0 += k0; x1 += k1 + 3u;
  TFR(17) TFR(29) TFR(16) TFR(24)
  x0 += k1; x1 += k2 + 4u;
  TFR(13) TFR(15) TFR(26) TFR(6)
  x0 += k2; x1 += k0 + 5u;
#undef TFR
  o0 = x0; o1 = x1;
}

// hi/lo truncation split
__device__ __forceinline__ void split2(float x, short& h, short& l) {
  unsigned int u = __float_as_uint(x);
  h = (short)(u >> 16);
  float hf = __uint_as_float(u & 0xFFFF0000u);
  l = (short)(__float_as_uint(x - hf) >> 16);
}

__device__ __forceinline__ float bred(float v, float* red, int n, int op) {
  int t = threadIdx.x;
  red[t] = v; __syncthreads();
  for (int s = n >> 1; s > 0; s >>= 1) {
    if (t < s) {
      float a = red[t], b = red[t + s];
      red[t] = (op == 0) ? (a + b) : (op == 1 ? fmaxf(a, b) : fminf(a, b));
    }
    __syncthreads();
  }
  float r = red[0]; __syncthreads();
  return r;
}

// ---------------- LN row stats for q/k/v (mu, rstd) -------------------------
__global__ void k_rowstats(const float* __restrict__ xq, const float* __restrict__ xk,
                           const float* __restrict__ xv, float* __restrict__ st) {
  int bid = blockIdx.x;
  int which = bid >> 12;
  int row = bid & 4095;
  const float* x = (which == 0) ? xq : (which == 1 ? xk : xv);
  float* stp = st + (size_t)which * 2 * NROWS;
  int t = threadIdx.x;             // 64
  float s = 0.f, sq = 0.f;
  for (int i = t; i < DD; i += 64) {
    float v = x[(size_t)row * DD + i];
    s += v; sq += v * v;
  }
  for (int off = 32; off; off >>= 1) { s += __shfl_down(s, off); sq += __shfl_down(sq, off); }
  if (t == 0) {
    float mu = s / 512.f;
    float var = sq / 512.f - mu * mu;
    stp[row * 2] = mu;
    stp[row * 2 + 1] = 1.0f / sqrtf(var + 1e-5f);
  }
}

// ---------------- per-(b,d) partials ---------------------------------------
__global__ void k_bd1(const float* __restrict__ x, float* __restrict__ psum,
                      float* __restrict__ psd2) {
  int c = blockIdx.x, b = blockIdx.y, d = threadIdx.x;
  const float* xb = x + (size_t)b * LL * DD + d;
  int l0 = c * 64;
  float prev = xb[(size_t)l0 * DD];
  float s = prev, sd2 = 0.f;
  for (int i = 1; i < 64; ++i) {
    float v = xb[(size_t)(l0 + i) * DD];
    s += v;
    float dd = v - prev; sd2 += dd * dd; prev = v;
  }
  if (c < 15) {
    float v = xb[(size_t)(l0 + 64) * DD];
    float dd = v - prev; sd2 += dd * dd;
  }
  psum[(b * 16 + c) * DD + d] = s;
  psd2[(b * 16 + c) * DD + d] = sd2;
}

// fused: xmean/vard + per-batch freq (one block per batch, 512 thr)
__global__ __launch_bounds__(512) void k_bd2f(const float* __restrict__ x,
                      const float* __restrict__ psum, const float* __restrict__ psd2,
                      float* __restrict__ xmean, float* __restrict__ frq) {
  __shared__ float red[512];
  int b = blockIdx.x, d = threadIdx.x;
  float s = 0.f, sd2 = 0.f;
  for (int c = 0; c < 16; ++c) { s += psum[(b * 16 + c) * DD + d]; sd2 += psd2[(b * 16 + c) * DD + d]; }
  xmean[b * DD + d] = s * (1.f / 1024.f);
  float S = x[(size_t)b * LL * DD + (size_t)1023 * DD + d] - x[(size_t)b * LL * DD + d];
  float vard = (sd2 - S * S / 1023.f) / 1022.f;
  red[d] = vard; __syncthreads();
  for (int s2 = 256; s2; s2 >>= 1) { if (d < s2) red[d] += red[d + s2]; __syncthreads(); }
  if (d == 0) frq[b] = red[0] / 512.f;
}

// ---------------- per-position stats ---------------------------------------
__global__ void k_perpos(const float* __restrict__ x, const float* __restrict__ xmean,
                         float* __restrict__ comb, float* __restrict__ dmw,
                         float* __restrict__ magw, float* __restrict__ chw,
                         float* __restrict__ fsvw, float* __restrict__ tiww) {
  __shared__ float red[128];
  int bid = blockIdx.x;
  int b = bid >> 10, l = bid & 1023;
  int t = threadIdx.x;               // 128
  const float* xb = x + (size_t)b * LL * DD;
  int s0 = (l - 2 > 0) ? (l - 2) : 0;
  int e0 = (l + 3 < 1024) ? (l + 3) : 1024;
  float n = (float)(e0 - s0);
  float s_comb = 0.f, s_dm = 0.f, s_mag = 0.f, s_ch = 0.f, s_var = 0.f, s_ti = 0.f;
  for (int d = t; d < DD; d += 128) {
    float x0 = xb[(size_t)l * DD + d];
    float d1 = (l + 1 <= 1023) ? fabsf(xb[(size_t)(l + 1) * DD + d] - x0) / 1.0f : 0.f;
    float d2 = (l + 2 <= 1023) ? fabsf(xb[(size_t)(l + 2) * DD + d] - x0) / 2.0f : 0.f;
    float d3 = (l + 3 <= 1023) ? fabsf(xb[(size_t)(l + 3) * DD + d] - x0) / 3.0f : 0.f;
    float d4 = (l + 4 <= 1023) ? fabsf(xb[(size_t)(l + 4) * DD + d] - x0) / 4.0f : 0.f;
    float d5 = (l + 5 <= 1023) ? fabsf(xb[(size_t)(l + 5) * DD + d] - x0) / 5.0f : 0.f;
    s_comb += 0.5f * d1 + 0.3f * d2 + 0.2f * d4;
    s_dm   += 0.4f * d1 + 0.3f * d2 + 0.2f * d3 + 0.1f * d5;
    s_mag  += x0 * x0;
    s_ch   += d1;
    s_ti   += (l <= 1022) ? fabsf(xb[(size_t)(l + 1) * DD + d] - xmean[b * DD + d]) : 0.f;
    float ws = 0.f, wq = 0.f;
    for (int r = s0; r < e0; ++r) { float v = xb[(size_t)r * DD + d]; ws += v; wq += v * v; }
    s_var += (wq - ws * ws / n) / (n - 1.f);
  }
  float r;
  r = bred(s_comb, red, 128, 0); if (t == 0) comb[bid] = r / 512.f;
  r = bred(s_dm,   red, 128, 0); if (t == 0) dmw[bid]  = r / 512.f;
  r = bred(s_mag,  red, 128, 0); if (t == 0) magw[bid] = sqrtf(r);
  r = bred(s_ch,   red, 128, 0); if (t == 0) chw[bid]  = r / 512.f;
  r = bred(s_var,  red, 128, 0); if (t == 0) fsvw[bid] = r / 512.f;
  r = bred(s_ti,   red, 128, 0); if (t == 0) tiww[bid] = r / 512.f;
}

// ---------------- per-batch: windows, keypoints + fused gumbel top-k --------
__global__ __launch_bounds__(1024) void k_batch(
    const float* __restrict__ comb, const float* __restrict__ dmw,
    const float* __restrict__ magw, const float* __restrict__ chw,
    const float* __restrict__ fsvw, const float* __restrict__ tiww,
    const float* __restrict__ frq,
    int* __restrict__ winlo, int* __restrict__ winhi,
    unsigned char* __restrict__ rowall, unsigned char* __restrict__ colf) {
  __shared__ float red[1024];
  __shared__ float sdm[1024];
  __shared__ int si[1024];
  __shared__ int anykp;
  int b = blockIdx.x, l = threadIdx.x;
  int idx = b * 1024 + l;
  float vcomb = comb[idx], vdm = dmw[idx], vmag = magw[idx];
  float vch = chw[idx], vfsv = fsvw[idx], vti = tiww[idx];
  float fqb = frq[b];
  sdm[l] = vdm;
  if (l == 0) anykp = 0;

  float cmin = bred(vcomb, red, 1024, 2);
  float cmax = bred(vcomb, red, 1024, 1);
  float impw = (vcomb - cmin) / (cmax - cmin + 1e-6f);
  int localw = (int)rintf(32.f * (0.5f + 0.5f * impw));
  localw = localw < 2 ? 2 : (localw > 64 ? 64 : localw);

  float tmin = bred(vti, red, 1024, 2);
  float tmax = bred(vti, red, 1024, 1);
  float tin = (vti - tmin) / (tmax - tmin + 1e-6f);
  int futw = (int)rintf(16.f * (0.5f + 0.5f * tin));
  futw = futw < 1 ? 1 : (futw > 16 ? 16 : futw);

  float dmean = bred(vdm, red, 1024, 0) / 1024.f;
  float dd = vdm - dmean;
  float dvar = bred(dd * dd, red, 1024, 0) / 1023.f;
  float thr = dmean + 0.5f * sqrtf(dvar);

  bool kp;
  if (l == 0 || l == 1023) kp = vdm > thr;
  else kp = (vdm > sdm[l - 1]) && (vdm > sdm[l + 1]) && (vdm > thr);
  if (kp) atomicOr(&anykp, 1);

  float fs = (l == 0 || l == 1023) ? 0.f : vfsv / (fqb + 1e-6f);
  float ig = vmag * 0.3f + vch * 0.4f + fs * 0.3f;
  float gmin = bred(ig, red, 1024, 2);
  float gmax = bred(ig, red, 1024, 1);   // bred syncs => anykp published
  float impn = (ig - gmin) / (gmax - gmin + 1e-6f);

  int any = anykp;
  winlo[idx] = l - localw;
  winhi[idx] = l + (localw > futw ? localw : futw);
  rowall[idx] = (any && kp) ? 1 : 0;
  bool fbcol = (l == 0 || l == 255 || l == 511 || l == 767 || l == 1023);
  colf[idx] = any ? (kp ? 1 : 0) : (fbcol ? 1 : 0);

  // ---- fused gumbel top-4 per 256-segment (layer = l>>8, j = l&255) -------
  int j = l & 255, seg0 = l & ~255;
  red[l] = impn; __syncthreads();
  for (int s = 128; s; s >>= 1) { if (j < s) red[l] += red[l + s]; __syncthreads(); }
  float ssum = red[seg0]; __syncthreads();
  float logit = logf(impn / ssum + 1e-20f);
  unsigned int o0, o1;
  threefry(0u, (unsigned int)idx, o0, o1);
  unsigned int bits = o0 ^ o1;
  float u = __uint_as_float((bits >> 9) | 0x3f800000u) - 1.0f;
  float g = -logf(-logf(u + 1e-20f) + 1e-20f);
  float key = logit + g;
  for (int pick = 0; pick < 4; ++pick) {
    red[l] = key; si[l] = j; __syncthreads();
    for (int s = 128; s; s >>= 1) {
      if (j < s) { if (red[l + s] > red[l]) { red[l] = red[l + s]; si[l] = si[l + s]; } }
      __syncthreads();
    }
    int w = si[seg0]; __syncthreads();
    if (j == w) { key = -1e30f; colf[idx] = 1; }
  }
}

// ---------------- split 5 weight matrices to frag-major hi/lo bf16 ----------
struct WArgs { const float* s[5]; u16* h[5]; u16* l[5]; };
__global__ void k_split_w(WArgs a) {
  int slot = blockIdx.x * 512 + threadIdx.x;   // 0..32767
  int lane = slot & 63;
  int kb = (slot >> 6) & 15, nt = slot >> 10;
  int c16 = lane & 15, g4 = lane >> 4;
  int n = nt * 16 + c16, k = kb * 32 + g4 * 8;
#pragma unroll
  for (int m = 0; m < 5; ++m) {
    const float* src = a.s[m] + (size_t)n * DD + k;
    float4 v0 = *(const float4*)src;
    float4 v1 = *(const float4*)(src + 4);
    float v[8] = {v0.x, v0.y, v0.z, v0.w, v1.x, v1.y, v1.z, v1.w};
    bf16x8 hv, lv;
#pragma unroll
    for (int j = 0; j < 8; ++j) {
      short hh, ll; split2(v[j], hh, ll);
      hv[j] = hh; lv[j] = ll;
    }
    *(bf16x8*)&a.h[m][(size_t)slot * 8] = hv;
    *(bf16x8*)&a.l[m][(size_t)slot * 8] = lv;
  }
}

// ---------------- QKV projection: MFMA split-bf16, frag-major outputs -------
struct QkvArgs {
  const float* X[3]; const float* stats[3]; const float* lnw[3]; const float* lnb[3];
  const float* bias[3]; const u16* Wh[3]; const u16* Wl[3];
  u16* oh[3]; u16* ol[3];
};
__global__ __launch_bounds__(256, 2) void k_gemm_qkv(QkvArgs a) {
  __shared__ float scr[4][1088];
  int z = blockIdx.z;
  int t = threadIdx.x, w = t >> 6, lane = t & 63, c16 = lane & 15, g4 = lane >> 4;
  int mbase = blockIdx.x * 256 + w * 64;
  int head = blockIdx.y, n0 = head * 64;
  const float* X = a.X[z];
  const float* stp = a.stats[z];
  const float* lnw = a.lnw[z];
  const float* lnb = a.lnb[z];
  const u16* Wh = a.Wh[z];
  const u16* Wl = a.Wl[z];
  const float* bias = a.bias[z];
  float scale = (z == 0) ? 0.125f : 1.0f;

  int rows[4]; float mu[4], rsd[4];
#pragma unroll
  for (int mi = 0; mi < 4; ++mi) {
    rows[mi] = mbase + mi * 16 + c16;
    mu[mi] = stp[rows[mi] * 2];
    rsd[mi] = stp[rows[mi] * 2 + 1];
  }
  f32x4 acc[4][4];
#pragma unroll
  for (int mi = 0; mi < 4; ++mi)
#pragma unroll
    for (int ni = 0; ni < 4; ++ni) acc[mi][ni] = (f32x4){0.f, 0.f, 0.f, 0.f};

  for (int k0 = 0; k0 < 512; k0 += 32) {
    int kk = k0 + g4 * 8;
    float4 w0 = *(const float4*)&lnw[kk];
    float4 w1 = *(const float4*)&lnw[kk + 4];
    float4 lb0 = *(const float4*)&lnb[kk];
    float4 lb1 = *(const float4*)&lnb[kk + 4];
    float lw[8] = {w0.x, w0.y, w0.z, w0.w, w1.x, w1.y, w1.z, w1.w};
    float lb[8] = {lb0.x, lb0.y, lb0.z, lb0.w, lb1.x, lb1.y, lb1.z, lb1.w};
    bf16x8 ah[4], al[4];
#pragma unroll
    for (int mi = 0; mi < 4; ++mi) {
      const float* xp = &X[(size_t)rows[mi] * DD + kk];
      float4 xa = *(const float4*)xp;
      float4 xb = *(const float4*)(xp + 4);
      float v[8] = {xa.x, xa.y, xa.z, xa.w, xb.x, xb.y, xb.z, xb.w};
#pragma unroll
      for (int j = 0; j < 8; ++j) {
        float y = fmaf((v[j] - mu[mi]) * rsd[mi], lw[j], lb[j]);
        short hh, ll; split2(y, hh, ll);
        ah[mi][j] = hh; al[mi][j] = ll;
      }
    }
    bf16x8 bh[4], bl[4];
    int kb32 = k0 >> 5;
#pragma unroll
    for (int ni = 0; ni < 4; ++ni) {
      size_t wo = wff(head * 4 + ni, kb32, lane);
      bh[ni] = *(const bf16x8*)&Wh[wo];
      bl[ni] = *(const bf16x8*)&Wl[wo];
    }
#pragma unroll
    for (int mi = 0; mi < 4; ++mi)
#pragma unroll
      for (int ni = 0; ni < 4; ++ni) {
        acc[mi][ni] = __builtin_amdgcn_mfma_f32_16x16x32_bf16(ah[mi], bh[ni], acc[mi][ni], 0, 0, 0);
        acc[mi][ni] = __builtin_amdgcn_mfma_f32_16x16x32_bf16(ah[mi], bl[ni], acc[mi][ni], 0, 0, 0);
        acc[mi][ni] = __builtin_amdgcn_mfma_f32_16x16x32_bf16(al[mi], bh[ni], acc[mi][ni], 0, 0, 0);
      }
  }

  int b = mbase >> 10, lr0 = mbase & 1023;
  size_t bhbase = (size_t)(b * HH + head) * BH_FRAG;
  if (z < 2) {
    u16* oh = a.oh[z]; u16* ol = a.ol[z];
    int row16 = lane >> 2, dseg = (lane & 3) * 16;
    float bs[16];
#pragma unroll
    for (int j = 0; j < 16; j += 4) {
      float4 bb = *(const float4*)&bias[n0 + dseg + j];
      bs[j] = bb.x; bs[j + 1] = bb.y; bs[j + 2] = bb.z; bs[j + 3] = bb.w;
    }
    int hf = dseg >> 5, g4a = (dseg >> 3) & 3;
#pragma unroll
    for (int mi = 0; mi < 4; ++mi) {
#pragma unroll
      for (int ni = 0; ni < 4; ++ni)
#pragma unroll
        for (int r = 0; r < 4; ++r)
          scr[w][(g4 * 4 + r) * 68 + ni * 16 + c16] = acc[mi][ni][r];
      float f[16];
#pragma unroll
      for (int j = 0; j < 16; j += 4) {
        float4 q = *(const float4*)&scr[w][row16 * 68 + dseg + j];
        f[j] = q.x; f[j + 1] = q.y; f[j + 2] = q.z; f[j + 3] = q.w;
      }
      bf16x8 fh[2], fl[2];
#pragma unroll
      for (int j = 0; j < 16; ++j) {
        short hh, ll; split2((f[j] + bs[j]) * scale, hh, ll);
        fh[j >> 3][j & 7] = hh; fl[j >> 3][j & 7] = ll;
      }
      int tile = (lr0 + mi * 16) >> 4;
      size_t ad1 = bhbase + akf(tile, hf, g4a * 16 + row16);
      size_t ad2 = bhbase + akf(tile, hf, (g4a + 1) * 16 + row16);
      *(bf16x8*)&oh[ad1] = fh[0]; *(bf16x8*)&oh[ad2] = fh[1];
      *(bf16x8*)&ol[ad1] = fl[0]; *(bf16x8*)&ol[ad2] = fl[1];
    }
  } else {
    u16* oh = a.oh[2]; u16* ol = a.ol[2];
#pragma unroll
    for (int ni = 0; ni < 4; ++ni) {
#pragma unroll
      for (int mi = 0; mi < 4; ++mi)
#pragma unroll
        for (int r = 0; r < 4; ++r)
          scr[w][(mi * 16 + g4 * 4 + r) * 17 + c16] = acc[mi][ni][r];
      float bb = bias[n0 + ni * 16 + c16];
#pragma unroll
      for (int kbloc = 0; kbloc < 2; ++kbloc) {
        bf16x8 hv, lv;
#pragma unroll
        for (int j = 0; j < 8; ++j) {
          float y = scr[w][(kbloc * 32 + g4 * 8 + j) * 17 + c16] + bb;
          short hh, ll; split2(y, hh, ll);
          hv[j] = hh; lv[j] = ll;
        }
        int kb = (lr0 >> 5) + kbloc;
        size_t ad = bhbase + vff(kb, ni, lane);
        *(bf16x8*)&oh[ad] = hv;
        *(bf16x8*)&ol[ad] = lv;
      }
    }
  }
}

// ---------------- flash attention: R6 structure + deep load batching --------
// grid (32,8,4) x 256 thr (4 waves): wave = (wq = w&1 q-subtile, wk = w>>1 kv half)
// Each wave: 16 q rows x 512 kv (8 chunks of 64, skip-capable). Flash combine.
// All 32 chunk fragments batched in regs before MFMA (sched_barrier pins order).
__global__ __launch_bounds__(256, 2) void k_attn_mfma(
    const u16* Qh, const u16* Ql, const u16* Kh, const u16* Kl,
    const u16* Vh, const u16* Vl,
    const int* __restrict__ winlo, const int* __restrict__ winhi,
    const unsigned char* __restrict__ rowall, const unsigned char* __restrict__ colf,
    u16* Ch, u16* Cl) {
  __shared__ float Pl_s[4][16][68];
  __shared__ unsigned char scolf[1024];
  __shared__ int schunk[16];
  int qt = blockIdx.x, h = blockIdx.y, b = blockIdx.z;
  int t = threadIdx.x, w = t >> 6, lane = t & 63;
  int c16 = lane & 15, g4 = lane >> 4;
  int wq = w & 1, wk = w >> 1;
  int q0 = qt * 32 + wq * 16;
  int qtile = q0 >> 4;
  size_t bhbase = (size_t)(b * HH + h) * BH_FRAG;

  for (int i = t; i < 1024; i += 256) scolf[i] = colf[b * 1024 + i];
  __syncthreads();
  if (t < 16) {
    int any = 0;
    const int* p32 = (const int*)&scolf[t * 64];
#pragma unroll
    for (int j = 0; j < 16; ++j) any |= p32[j];
    schunk[t] = any;
  }

  const u16* Qfh = Qh + bhbase;
  const u16* Qfl = Ql + bhbase;
  bf16x8 qh0 = *(const bf16x8*)&Qfh[akf(qtile, 0, lane)];
  bf16x8 qh1 = *(const bf16x8*)&Qfh[akf(qtile, 1, lane)];
  bf16x8 ql0 = *(const bf16x8*)&Qfl[akf(qtile, 0, lane)];
  bf16x8 ql1 = *(const bf16x8*)&Qfl[akf(qtile, 1, lane)];

  int elo[4], ehi[4];
#pragma unroll
  for (int r = 0; r < 4; ++r) {
    int row = b * 1024 + q0 + g4 * 4 + r;
    int ra = rowall[row];
    elo[r] = ra ? 0 : winlo[row];
    ehi[r] = ra ? 1023 : winhi[row];
  }
  int tlo = min(min(elo[0], elo[1]), min(elo[2], elo[3]));
  int thi = max(max(ehi[0], ehi[1]), max(ehi[2], ehi[3]));
  tlo = min(tlo, __shfl_xor(tlo, 16)); tlo = min(tlo, __shfl_xor(tlo, 32));
  thi = max(thi, __shfl_xor(thi, 16)); thi = max(thi, __shfl_xor(thi, 32));
  __syncthreads();   // scolf + schunk ready

  const u16* Kfh = Kh + bhbase;
  const u16* Kfl = Kl + bhbase;
  const u16* Vfh = Vh + bhbase;
  const u16* Vfl = Vl + bhbase;

  float m[4] = {-1e30f, -1e30f, -1e30f, -1e30f};
  float lsum[4] = {0.f, 0.f, 0.f, 0.f};
  f32x4 accO[4];
#pragma unroll
  for (int dt = 0; dt < 4; ++dt) accO[dt] = (f32x4){0.f, 0.f, 0.f, 0.f};

  int kvbase = wk * 512;
  for (int kt = 0; kt < 8; ++kt) {
    int kb0 = kvbase + kt * 64;
    if (!schunk[kb0 >> 6] && (kb0 > thi || kb0 + 63 < tlo)) continue;
    // ---- batch ALL chunk fragments: 16 K + 16 V loads in flight ------------
    bf16x8 kf[4][4];
#pragma unroll
    for (int tt = 0; tt < 4; ++tt) {
      int kt16 = (kb0 >> 4) + tt;
      kf[tt][0] = *(const bf16x8*)&Kfh[akf(kt16, 0, lane)];
      kf[tt][1] = *(const bf16x8*)&Kfh[akf(kt16, 1, lane)];
      kf[tt][2] = *(const bf16x8*)&Kfl[akf(kt16, 0, lane)];
      kf[tt][3] = *(const bf16x8*)&Kfl[akf(kt16, 1, lane)];
    }
    bf16x8 vf[2][4][2];
#pragma unroll
    for (int ks = 0; ks < 2; ++ks) {
      int kb = (kb0 >> 5) + ks;
#pragma unroll
      for (int dt = 0; dt < 4; ++dt) {
        vf[ks][dt][0] = *(const bf16x8*)&Vfh[vff(kb, dt, lane)];
        vf[ks][dt][1] = *(const bf16x8*)&Vfl[vff(kb, dt, lane)];
      }
    }
    __builtin_amdgcn_sched_barrier(0);   // pin: all loads issued before MFMA
    // ---- QK^T --------------------------------------------------------------
    f32x4 s[4];
    __builtin_amdgcn_s_setprio(1);
#pragma unroll
    for (int tt = 0; tt < 4; ++tt) {
      f32x4 a = (f32x4){0.f, 0.f, 0.f, 0.f};
      a = __builtin_amdgcn_mfma_f32_16x16x32_bf16(qh0, kf[tt][0], a, 0, 0, 0);
      a = __builtin_amdgcn_mfma_f32_16x16x32_bf16(qh1, kf[tt][1], a, 0, 0, 0);
      a = __builtin_amdgcn_mfma_f32_16x16x32_bf16(qh0, kf[tt][2], a, 0, 0, 0);
      a = __builtin_amdgcn_mfma_f32_16x16x32_bf16(qh1, kf[tt][3], a, 0, 0, 0);
      a = __builtin_amdgcn_mfma_f32_16x16x32_bf16(ql0, kf[tt][0], a, 0, 0, 0);
      a = __builtin_amdgcn_mfma_f32_16x16x32_bf16(ql1, kf[tt][1], a, 0, 0, 0);
      s[tt] = a;
    }
    __builtin_amdgcn_s_setprio(0);
    // ---- mask + online softmax ---------------------------------------------
    float mr[4] = {-1e30f, -1e30f, -1e30f, -1e30f};
#pragma unroll
    for (int tt = 0; tt < 4; ++tt) {
      int kv = kb0 + tt * 16 + c16;
      bool cf = scolf[kv] != 0;
#pragma unroll
      for (int r = 0; r < 4; ++r) {
        bool vis = cf || (kv >= elo[r] && kv <= ehi[r]);
        float v = vis ? s[tt][r] : -1e9f;
        s[tt][r] = v;
        mr[r] = fmaxf(mr[r], v);
      }
    }
#pragma unroll
    for (int off = 1; off < 16; off <<= 1)
#pragma unroll
      for (int r = 0; r < 4; ++r) mr[r] = fmaxf(mr[r], __shfl_xor(mr[r], off));
    float sc[4], rs[4];
#pragma unroll
    for (int r = 0; r < 4; ++r) {
      float mn = fmaxf(m[r], mr[r]);
      sc[r] = __expf(m[r] - mn);
      m[r] = mn;
      rs[r] = 0.f;
    }
#pragma unroll
    for (int tt = 0; tt < 4; ++tt)
#pragma unroll
      for (int r = 0; r < 4; ++r) {
        float p = __expf(s[tt][r] - m[r]);
        s[tt][r] = p;
        rs[r] += p;
      }
#pragma unroll
    for (int off = 1; off < 16; off <<= 1)
#pragma unroll
      for (int r = 0; r < 4; ++r) rs[r] += __shfl_xor(rs[r], off);
#pragma unroll
    for (int r = 0; r < 4; ++r) lsum[r] = lsum[r] * sc[r] + rs[r];
#pragma unroll
    for (int dt = 0; dt < 4; ++dt)
#pragma unroll
      for (int r = 0; r < 4; ++r) accO[dt][r] *= sc[r];
    // ---- P -> per-wave LDS transpose, then PV ------------------------------
#pragma unroll
    for (int tt = 0; tt < 4; ++tt)
#pragma unroll
      for (int r = 0; r < 4; ++r)
        Pl_s[w][g4 * 4 + r][tt * 16 + c16] = s[tt][r];
#pragma unroll
    for (int ks = 0; ks < 2; ++ks) {
      const float* prow = &Pl_s[w][c16][ks * 32 + g4 * 8];
      float4 pa = *(const float4*)(prow);
      float4 pb = *(const float4*)(prow + 4);
      float pv[8] = {pa.x, pa.y, pa.z, pa.w, pb.x, pb.y, pb.z, pb.w};
      bf16x8 pah, pal;
#pragma unroll
      for (int j = 0; j < 8; ++j) {
        short hh, ll; split2(pv[j], hh, ll);
        pah[j] = hh; pal[j] = ll;
      }
      __builtin_amdgcn_s_setprio(1);
#pragma unroll
      for (int dt = 0; dt < 4; ++dt) {
        accO[dt] = __builtin_amdgcn_mfma_f32_16x16x32_bf16(pah, vf[ks][dt][0], accO[dt], 0, 0, 0);
        accO[dt] = __builtin_amdgcn_mfma_f32_16x16x32_bf16(pah, vf[ks][dt][1], accO[dt], 0, 0, 0);
        accO[dt] = __builtin_amdgcn_mfma_f32_16x16x32_bf16(pal, vf[ks][dt][0], accO[dt], 0, 0, 0);
      }
      __builtin_amdgcn_s_setprio(0);
    }
  }
  // ---- publish partials, combine halves, frag-store CTX ---------------------
#pragma unroll
  for (int dt = 0; dt < 4; ++dt)
#pragma unroll
    for (int r = 0; r < 4; ++r)
      Pl_s[w][g4 * 4 + r][dt * 16 + c16] = accO[dt][r];
  if (c16 == 0) {
#pragma unroll
    for (int r = 0; r < 4; ++r) {
      Pl_s[w][g4 * 4 + r][64] = m[r];
      Pl_s[w][g4 * 4 + r][65] = lsum[r];
    }
  }
  __syncthreads();
  if (w < 2) {
    float ca[4], cb[4], inv[4];
#pragma unroll
    for (int r = 0; r < 4; ++r) {
      int row = g4 * 4 + r;
      float mb = Pl_s[w + 2][row][64];
      float lb = Pl_s[w + 2][row][65];
      float mm = fmaxf(m[r], mb);
      ca[r] = __expf(m[r] - mm);
      cb[r] = __expf(mb - mm);
      float lt = lsum[r] * ca[r] + lb * cb[r];
      inv[r] = 1.0f / lt;
    }
    float y[4][4];
#pragma unroll
    for (int dt = 0; dt < 4; ++dt)
#pragma unroll
      for (int r = 0; r < 4; ++r)
        y[dt][r] = (accO[dt][r] * ca[r] + Pl_s[w + 2][g4 * 4 + r][dt * 16 + c16] * cb[r]) * inv[r];
#pragma unroll
    for (int dt = 0; dt < 4; ++dt)
#pragma unroll
      for (int r = 0; r < 4; ++r)
        Pl_s[w][g4 * 4 + r][dt * 16 + c16] = y[dt][r];
    int row16 = lane >> 2, dseg = (lane & 3) * 16;
    int hf = dseg >> 5, g4a = (dseg >> 3) & 3;
    float f[16];
#pragma unroll
    for (int j = 0; j < 16; j += 4) {
      float4 q = *(const float4*)&Pl_s[w][row16][dseg + j];
      f[j] = q.x; f[j + 1] = q.y; f[j + 2] = q.z; f[j + 3] = q.w;
    }
    bf16x8 fh[2], fl[2];
#pragma unroll
    for (int j = 0; j < 16; ++j) {
      short hh, ll; split2(f[j], hh, ll);
      fh[j >> 3][j & 7] = hh; fl[j >> 3][j & 7] = ll;
    }
    size_t ad1 = bhbase + akf(qtile, hf, g4a * 16 + row16);
    size_t ad2 = bhbase + akf(qtile, hf, (g4a + 1) * 16 + row16);
    *(bf16x8*)&Ch[ad1] = fh[0]; *(bf16x8*)&Ch[ad2] = fh[1];
    *(bf16x8*)&Cl[ad1] = fl[0]; *(bf16x8*)&Cl[ad2] = fl[1];
  }
}

// ---------------- final dual GEMM (MFMA) ------------------------------------
struct OutArgs {
  const u16* Ch; const u16* Cl; const float* XQ;
  const u16* Woh; const u16* Wol; const u16* Wgh; const u16* Wgl;
  const float* bo; const float* bg; float* out;
};
__global__ __launch_bounds__(256, 2) void k_gemm_out(OutArgs a) {
  int t = threadIdx.x, w = t >> 6, lane = t & 63, c16 = lane & 15, g4 = lane >> 4;
  int mbase = blockIdx.x * 256 + w * 64;
  int n0 = blockIdx.y * 32;
  int rows[4];
#pragma unroll
  for (int mi = 0; mi < 4; ++mi) rows[mi] = mbase + mi * 16 + c16;
  int bidx = mbase >> 10, lr0 = mbase & 1023;
  f32x4 accO[4][2], accG[4][2];
#pragma unroll
  for (int mi = 0; mi < 4; ++mi)
#pragma unroll
    for (int ni = 0; ni < 2; ++ni) {
      accO[mi][ni] = (f32x4){0.f, 0.f, 0.f, 0.f};
      accG[mi][ni] = (f32x4){0.f, 0.f, 0.f, 0.f};
    }
  for (int k0 = 0; k0 < 512; k0 += 32) {
    int kk = k0 + g4 * 8;
    int hsel = kk >> 6, hf = (kk >> 5) & 1;
    int kb32 = k0 >> 5;
    bf16x8 ch[4], cl[4], gh[4], gl[4];
#pragma unroll
    for (int mi = 0; mi < 4; ++mi) {
      int ctile = (lr0 + mi * 16) >> 4;
      size_t cb = (size_t)(bidx * HH + hsel) * BH_FRAG + akf(ctile, hf, lane);
      ch[mi] = *(const bf16x8*)&a.Ch[cb];
      cl[mi] = *(const bf16x8*)&a.Cl[cb];
      const float* xp = &a.XQ[(size_t)rows[mi] * DD + kk];
      float4 xa = *(const float4*)xp;
      float4 xb = *(const float4*)(xp + 4);
      float v[8] = {xa.x, xa.y, xa.z, xa.w, xb.x, xb.y, xb.z, xb.w};
#pragma unroll
      for (int j = 0; j < 8; ++j) {
        short hh, ll; split2(v[j], hh, ll);
        gh[mi][j] = hh; gl[mi][j] = ll;
      }
    }
    bf16x8 woh[2], wol[2], wgh[2], wgl[2];
#pragma unroll
    for (int ni = 0; ni < 2; ++ni) {
      size_t wo = wff((n0 >> 4) + ni, kb32, lane);
      woh[ni] = *(const bf16x8*)&a.Woh[wo];
      wol[ni] = *(const bf16x8*)&a.Wol[wo];
      wgh[ni] = *(const bf16x8*)&a.Wgh[wo];
      wgl[ni] = *(const bf16x8*)&a.Wgl[wo];
    }
#pragma unroll
    for (int mi = 0; mi < 4; ++mi)
#pragma unroll
      for (int ni = 0; ni < 2; ++ni) {
        accO[mi][ni] = __builtin_amdgcn_mfma_f32_16x16x32_bf16(ch[mi], woh[ni], accO[mi][ni], 0, 0, 0);
        accO[mi][ni] = __builtin_amdgcn_mfma_f32_16x16x32_bf16(ch[mi], wol[ni], accO[mi][ni], 0, 0, 0);
        accO[mi][ni] = __builtin_amdgcn_mfma_f32_16x16x32_bf16(cl[mi], woh[ni], accO[mi][ni], 0, 0, 0);
        accG[mi][ni] = __builtin_amdgcn_mfma_f32_16x16x32_bf16(gh[mi], wgh[ni], accG[mi][ni], 0, 0, 0);
        accG[mi][ni] = __builtin_amdgcn_mfma_f32_16x16x32_bf16(gh[mi], wgl[ni], accG[mi][ni], 0, 0, 0);
        accG[mi][ni] = __builtin_amdgcn_mfma_f32_16x16x32_bf16(gl[mi], wgh[ni], accG[mi][ni], 0, 0, 0);
      }
  }
#pragma unroll
  for (int mi = 0; mi < 4; ++mi)
#pragma unroll
    for (int ni = 0; ni < 2; ++ni) {
      int n = n0 + ni * 16 + c16;
      float bo = a.bo[n], bg = a.bg[n];
#pragma unroll
      for (int r = 0; r < 4; ++r) {
        int l = mbase + mi * 16 + g4 * 4 + r;
        float ov = accO[mi][ni][r] + bo;
        float gp = accG[mi][ni][r] + bg;
        float gate = 1.0f / (1.0f + __expf(-gp));
        a.out[(size_t)l * DD + n] = gate * ov;
      }
    }
}

// ---------------- host launch ----------------------------------------------
extern "C" void kernel_launch(void* const* d_in, const int* in_sizes, int n_in,
                              void* d_out, int out_size, void* d_ws, size_t ws_size,
                              hipStream_t stream) {
  (void)in_sizes; (void)n_in; (void)out_size; (void)ws_size;
  const float* xq = (const float*)d_in[0];
  const float* xk = (const float*)d_in[1];
  const float* xv = (const float*)d_in[2];
  const float* Wq = (const float*)d_in[3];
  const float* bq = (const float*)d_in[4];
  const float* Wk = (const float*)d_in[5];
  const float* bk = (const float*)d_in[6];
  const float* Wv = (const float*)d_in[7];
  const float* bv = (const float*)d_in[8];
  const float* Wo = (const float*)d_in[9];
  const float* bo = (const float*)d_in[10];
  const float* Wg = (const float*)d_in[11];
  const float* bg = (const float*)d_in[12];
  const float* lqw = (const float*)d_in[13];
  const float* lqb = (const float*)d_in[14];
  const float* lkw = (const float*)d_in[15];
  const float* lkb = (const float*)d_in[16];
  const float* lvw = (const float*)d_in[17];
  const float* lvb = (const float*)d_in[18];
  float* out = (float*)d_out;

  char* base = (char*)d_ws;
  u16* Qh = (u16*)(base + (size_t)0 * MiB);
  u16* Ql = (u16*)(base + (size_t)4 * MiB);
  u16* Kh = (u16*)(base + (size_t)8 * MiB);
  u16* Kl = (u16*)(base + (size_t)12 * MiB);
  u16* Vh = (u16*)(base + (size_t)16 * MiB);
  u16* Vl = (u16*)(base + (size_t)20 * MiB);
  u16* Wsp = (u16*)(base + (size_t)24 * MiB);
  u16 *Wqh = Wsp, *Wql = Wsp + 262144, *Wkh = Wsp + 2 * 262144, *Wkl = Wsp + 3 * 262144;
  u16 *Wvh = Wsp + 4 * 262144, *Wvl = Wsp + 5 * 262144;
  u16 *Woh = Wsp + 6 * 262144, *Wol = Wsp + 7 * 262144;
  u16 *Wgh = Wsp + 8 * 262144, *Wgl = Wsp + 9 * 262144;
  float* st = (float*)(base + (size_t)29 * MiB);          // 24576 f
  float* tr = (float*)(base + (size_t)29 * MiB + 131072);
  float* xmean = tr;               // 2048
  float* frq = xmean + 2048;       // 64
  float* comb = frq + 64;
  float* dmw = comb + 4096;
  float* magw = dmw + 4096;
  float* chw = magw + 4096;
  float* fsvw = chw + 4096;
  float* tiww = fsvw + 4096;
  float* psum = tiww + 4096;       // 32768
  float* psd2 = psum + 32768;      // 32768
  int* winlo = (int*)(base + (size_t)30 * MiB);
  int* winhi = winlo + NROWS;
  unsigned char* rowallp = (unsigned char*)(winhi + NROWS);
  unsigned char* colfp = rowallp + NROWS;

  // mask pipeline
  k_rowstats<<<3 * NROWS, 64, 0, stream>>>(xq, xk, xv, st);
  k_bd1<<<dim3(16, BB), 512, 0, stream>>>(xq, psum, psd2);
  k_bd2f<<<BB, 512, 0, stream>>>(xq, psum, psd2, xmean, frq);
  k_perpos<<<NROWS, 128, 0, stream>>>(xq, xmean, comb, dmw, magw, chw, fsvw, tiww);
  k_batch<<<BB, 1024, 0, stream>>>(comb, dmw, magw, chw, fsvw, tiww, frq,
                                   winlo, winhi, rowallp, colfp);

  // weight splits (fragment-major)
  WArgs wa;
  wa.s[0] = Wq; wa.s[1] = Wk; wa.s[2] = Wv; wa.s[3] = Wo; wa.s[4] = Wg;
  wa.h[0] = Wqh; wa.h[1] = Wkh; wa.h[2] = Wvh; wa.h[3] = Woh; wa.h[4] = Wgh;
  wa.l[0] = Wql; wa.l[1] = Wkl; wa.l[2] = Wvl; wa.l[3] = Wol; wa.l[4] = Wgl;
  k_split_w<<<64, 512, 0, stream>>>(wa);

  // QKV projections
  QkvArgs qa;
  qa.X[0] = xq; qa.X[1] = xk; qa.X[2] = xv;
  qa.stats[0] = st; qa.stats[1] = st + 2 * NROWS; qa.stats[2] = st + 4 * NROWS;
  qa.lnw[0] = lqw; qa.lnw[1] = lkw; qa.lnw[2] = lvw;
  qa.lnb[0] = lqb; qa.lnb[1] = lkb; qa.lnb[2] = lvb;
  qa.bias[0] = bq; qa.bias[1] = bk; qa.bias[2] = bv;
  qa.Wh[0] = Wqh; qa.Wh[1] = Wkh; qa.Wh[2] = Wvh;
  qa.Wl[0] = Wql; qa.Wl[1] = Wkl; qa.Wl[2] = Wvl;
  qa.oh[0] = Qh; qa.oh[1] = Kh; qa.oh[2] = Vh;
  qa.ol[0] = Ql; qa.ol[1] = Kl; qa.ol[2] = Vl;
  k_gemm_qkv<<<dim3(16, 8, 3), 256, 0, stream>>>(qa);

  // attention (R6 grid; deep-batched loads; CTX into Q buffers)
  k_attn_mfma<<<dim3(32, HH, BB), 256, 0, stream>>>(Qh, Ql, Kh, Kl, Vh, Vl,
                                                    winlo, winhi, rowallp, colfp,
                                                    Qh, Ql);

  // output dual GEMM
  OutArgs oa;
  oa.Ch = Qh; oa.Cl = Ql; oa.XQ = xq;
  oa.Woh = Woh; oa.Wol = Wol; oa.Wgh = Wgh; oa.Wgl = Wgl;
  oa.bo = bo; oa.bg = bg; oa.out = out;
  k_gemm_out<<<dim3(16, 16), 256, 0, stream>>>(oa);
}